// Round 1
// baseline (186.559 us; speedup 1.0000x reference)
//
#include <hip/hip_runtime.h>
#include <hip/hip_bf16.h>
#include <stdint.h>

#define L1DIM 1536
#define NOUT  144           // 128 (W1) + 16 (Wf) layer-1 outputs
#define BK    64            // K-chunk per staging iteration
#define MTILE 32            // rows per block
#define NCHUNK16 1152       // (BK/8)*NOUT*8 bf16 = 18432 B = 1152 x 16B

typedef __bf16 bf16;
typedef __bf16 bf16x8 __attribute__((ext_vector_type(8)));
typedef float  floatx4 __attribute__((ext_vector_type(4)));

// ---------------------------------------------------------------------------
// Prep: pack [W1;Wf] (144 x 1536 fp32) into bf16, B-fragment-friendly layout:
//   pw[(k/8)*144 + n][j] , j=0..7  (16 B per (k-octet, n) pair)
// so a BK=64 K-slab is one contiguous 18432 B block.
// ---------------------------------------------------------------------------
__global__ void pack_weights(const float* __restrict__ W1,
                             const float* __restrict__ Wf,
                             bf16* __restrict__ pw) {
    int t = blockIdx.x * blockDim.x + threadIdx.x;   // 0 .. 192*144-1
    if (t >= 192 * NOUT) return;
    int o = t / NOUT;        // k-octet 0..191
    int n = t % NOUT;        // output feature 0..143
    const float* src = (n < 128) ? (W1 + (size_t)n * L1DIM + o * 8)
                                 : (Wf + (size_t)(n - 128) * L1DIM + o * 8);
    bf16* dst = pw + (size_t)t * 8;
#pragma unroll
    for (int j = 0; j < 8; j++) dst[j] = (bf16)src[j];
}

__device__ __forceinline__ void gload_lds16(const void* g, void* l) {
    __builtin_amdgcn_global_load_lds(
        (const __attribute__((address_space(1))) void*)g,
        (__attribute__((address_space(3))) void*)l, 16, 0, 0);
}

// ---------------------------------------------------------------------------
// Fused kernel: layer-1 GEMM (bf16 MFMA) + bucket select + layer2 + layer3.
// Block: 256 threads (4 waves), 32 rows. Wave w: M-subtile (w&1)*16,
// N-tiles [0..4] for w>>1==0, [5..8] for w>>1==1.
// ---------------------------------------------------------------------------
__global__ __launch_bounds__(256) void layerstacks_main(
    const float* __restrict__ x, const int* __restrict__ lsidx,
    const bf16* __restrict__ pw,
    const float* __restrict__ b1, const float* __restrict__ bf_,
    const float* __restrict__ W2, const float* __restrict__ b2,
    const float* __restrict__ Wo, const float* __restrict__ bo,
    float* __restrict__ out)
{
    __shared__ bf16  lb[8 * NOUT * 8];     // one BK=64 slab, 18432 B
    __shared__ float ep[MTILE][148];       // layer-1 results, padded (no bank conflicts)

    const int tid  = threadIdx.x;
    const int wv   = tid >> 6;
    const int ln   = tid & 63;
    const int quad = ln >> 4;
    const int lm   = ln & 15;

    const int R0  = blockIdx.x * MTILE;
    const int ms  = wv & 1;                 // M-subtile
    const int nh  = wv >> 1;                // N half
    const int nt0 = nh ? 5 : 0;
    const int ntn = nh ? 4 : 5;

    const float* xrow = x + (size_t)(R0 + ms * 16 + lm) * L1DIM;

    floatx4 acc[5];
#pragma unroll
    for (int i = 0; i < 5; i++) acc[i] = (floatx4){0.f, 0.f, 0.f, 0.f};

    for (int ki = 0; ki < L1DIM / BK; ki++) {
        const int k0 = ki * BK;
        __syncthreads();   // previous iter's lb reads complete
        // ---- stage B slab (contiguous 18432 B) via async global->LDS ----
        {
            const bf16* src = pw + (size_t)(k0 / 8) * NOUT * 8;
            for (int base = wv * 64; base < NCHUNK16; base += 256) {
                gload_lds16(src + (size_t)(base + ln) * 8, &lb[(size_t)base * 8 + ln * 8]);
            }
        }
        // ---- A fragments straight from global (full 128B lines), cvt to bf16 ----
        float4 a0 = *(const float4*)(xrow + k0 + quad * 8);
        float4 a1 = *(const float4*)(xrow + k0 + quad * 8 + 4);
        float4 a2 = *(const float4*)(xrow + k0 + 32 + quad * 8);
        float4 a3 = *(const float4*)(xrow + k0 + 32 + quad * 8 + 4);
        bf16x8 af0, af1;
        {
            float t0[8] = {a0.x, a0.y, a0.z, a0.w, a1.x, a1.y, a1.z, a1.w};
            float t1[8] = {a2.x, a2.y, a2.z, a2.w, a3.x, a3.y, a3.z, a3.w};
#pragma unroll
            for (int j = 0; j < 8; j++) { af0[j] = (bf16)t0[j]; af1[j] = (bf16)t1[j]; }
        }
        __syncthreads();   // staging complete
#pragma unroll
        for (int t = 0; t < 5; t++) {
            if (t < ntn) {
                const int nt = nt0 + t;
                bf16x8 bf0 = *(const bf16x8*)&lb[((quad)     * NOUT + nt * 16 + lm) * 8];
                bf16x8 bf1 = *(const bf16x8*)&lb[((4 + quad) * NOUT + nt * 16 + lm) * 8];
                acc[t] = __builtin_amdgcn_mfma_f32_16x16x32_bf16(af0, bf0, acc[t], 0, 0, 0);
                acc[t] = __builtin_amdgcn_mfma_f32_16x16x32_bf16(af1, bf1, acc[t], 0, 0, 0);
            }
        }
    }

    // ---- write layer-1 results to LDS (C layout: row=quad*4+r, col=lm) ----
#pragma unroll
    for (int t = 0; t < 5; t++) {
        if (t < ntn) {
            const int nt = nt0 + t;
#pragma unroll
            for (int r = 0; r < 4; r++)
                ep[ms * 16 + quad * 4 + r][nt * 16 + lm] = acc[t][r];
        }
    }
    __syncthreads();

    // ---- epilogue: 8 threads per row ----
    const int er   = tid >> 3;          // row in tile, 0..31
    const int sub  = tid & 7;           // output-group, 0..7
    const int grow = R0 + er;
    const int bkt  = lsidx[grow];

    const float l1c15 = ep[er][bkt * 16 + 15] + b1[bkt * 16 + 15];
    const float l1f15 = ep[er][128 + 15] + bf_[15];

    float l1x[30];
#pragma unroll
    for (int j = 0; j < 15; j++) {
        float tj = (ep[er][bkt * 16 + j] + b1[bkt * 16 + j])
                 + (ep[er][128 + j]      + bf_[j]);
        float sq = tj * tj * (127.0f / 128.0f);
        l1x[j]      = fminf(fmaxf(sq, 0.f), 1.f);
        l1x[15 + j] = fminf(fmaxf(tj, 0.f), 1.f);
    }

    float part = 0.f;
#pragma unroll
    for (int o = 0; o < 8; o++) {
        const int oi = bkt * 64 + sub * 8 + o;
        const float2* wrow = (const float2*)(W2 + oi * 30);   // 8B-aligned (30*4*oi)
        float a = b2[oi];
#pragma unroll
        for (int j2 = 0; j2 < 15; j2++) {
            float2 w = wrow[j2];
            a += l1x[2 * j2] * w.x + l1x[2 * j2 + 1] * w.y;
        }
        a = fminf(fmaxf(a, 0.f), 1.f);
        part += a * Wo[oi];
    }
    part += __shfl_xor(part, 1);
    part += __shfl_xor(part, 2);
    part += __shfl_xor(part, 4);
    if (sub == 0) out[grow] = part + bo[bkt] + l1c15 + l1f15;
}

extern "C" void kernel_launch(void* const* d_in, const int* in_sizes, int n_in,
                              void* d_out, int out_size, void* d_ws, size_t ws_size,
                              hipStream_t stream) {
    const float* x   = (const float*)d_in[0];
    const int*   idx = (const int*)  d_in[1];
    const float* W1  = (const float*)d_in[2];
    const float* b1  = (const float*)d_in[3];
    const float* Wf  = (const float*)d_in[4];
    const float* bf  = (const float*)d_in[5];
    const float* W2  = (const float*)d_in[6];
    const float* b2  = (const float*)d_in[7];
    const float* Wo  = (const float*)d_in[8];
    const float* bo  = (const float*)d_in[9];
    float* out = (float*)d_out;
    bf16*  pw  = (bf16*)d_ws;                 // 442368 B of workspace

    pack_weights<<<dim3((192 * NOUT + 255) / 256), dim3(256), 0, stream>>>(W1, Wf, pw);
    layerstacks_main<<<dim3(16384 / MTILE), dim3(256), 0, stream>>>(
        x, idx, pw, b1, bf, W2, b2, Wo, bo, out);
}